// Round 5
// baseline (6882.030 us; speedup 1.0000x reference)
//
#include <hip/hip_runtime.h>
#include <hip/hip_bf16.h>

// Encoder: 2-layer LSTM, B=64 T=256 E=512 H=1024.
// Device dtypes: floats are f32 (per reference); src/lengths int32. Output f32.
// Internal: bf16 weights/activations for MFMA, f32 accum, f32 c-state.
// Out: outputs[64][256][1024] | h_n[2][64][1024] | c_n[2][64][1024]  (f32)

typedef short bf16x8 __attribute__((ext_vector_type(8)));
typedef float f32x4 __attribute__((ext_vector_type(4)));

__device__ __forceinline__ float bf2f(ushort u) {
  union { unsigned int i; float f; } v; v.i = ((unsigned int)u) << 16; return v.f;
}
__device__ __forceinline__ ushort f2bf(float f) {
  union { float f; unsigned int i; } v; v.f = f;
  unsigned int r = v.i + 0x7fffu + ((v.i >> 16) & 1u);
  return (ushort)(r >> 16);
}

// ---------------- transpose+convert: W f32 [K][4096] -> WT bf16 [4096][K] ------
__global__ __launch_bounds__(256) void transpose_cvt(const float* __restrict__ W,
                                                     ushort* __restrict__ WT, int K) {
  __shared__ ushort t[64][65];
  int bn = blockIdx.x * 64;
  int bk = blockIdx.y * 64;
  for (int s = threadIdx.x; s < 4096; s += 256) {
    int kl = s >> 6, nl = s & 63;
    t[kl][nl] = f2bf(W[(size_t)(bk + kl) * 4096 + bn + nl]);
  }
  __syncthreads();
  for (int s = threadIdx.x; s < 4096; s += 256) {
    int nl = s >> 6, kl = s & 63;
    WT[(size_t)(bn + nl) * K + bk + kl] = t[kl][nl];
  }
}

// ---------------- G_chunk = A @ W + b for 4096 rows (64 timesteps x 64 batch) ----
// A: f32 (gathered emb rows) when AF32, else bf16 rows [m][K].
// WT bf16 [4096][K]. G bf16 [4096][4096]. LDS 128x64 tiles, XOR swizzle (T2).
__device__ __forceinline__ int swz(int row, int kElem) {
  int byte = row * 128 + kElem * 2;
  return byte ^ ((row & 7) << 4);
}

template <bool AF32>
__global__ __launch_bounds__(256) void gemm_xw(const void* __restrict__ Av,
                                               const int* __restrict__ gather, int tbase,
                                               const ushort* __restrict__ WT,
                                               const float* __restrict__ bias,
                                               ushort* __restrict__ G, int K) {
  int bx = blockIdx.x & 31;   // n tile (N=4096/128)
  int by = blockIdx.x >> 5;   // m tile (M=4096/128)
  int tid = threadIdx.x;
  int w = tid >> 6, l = tid & 63;
  int wr = w >> 1, wc = w & 1;
  int lr = l & 15, lk = (l >> 4) * 8;

  __shared__ alignas(16) char At[128 * 64 * 2];
  __shared__ alignas(16) char Bt[128 * 64 * 2];

  int srow = tid >> 3;          // 0..31
  int skof = (tid & 7) * 8;     // element offset 0..56

  size_t aoff[4];
  const ushort* brow[4];
#pragma unroll
  for (int c2 = 0; c2 < 4; ++c2) {
    int m = by * 128 + c2 * 32 + srow;
    long idx = gather ? (long)gather[(m & 63) * 256 + tbase + (m >> 6)] : (long)m;
    aoff[c2] = (size_t)idx * K + skof;
    int n = bx * 128 + c2 * 32 + srow;
    brow[c2] = WT + (size_t)n * K + skof;
  }

  f32x4 zero = {0.f, 0.f, 0.f, 0.f};
  f32x4 acc[4][4];
#pragma unroll
  for (int i = 0; i < 4; ++i)
#pragma unroll
    for (int j = 0; j < 4; ++j) acc[i][j] = zero;

  for (int kc = 0; kc < K; kc += 64) {
    bf16x8 ar[4], br[4];
#pragma unroll
    for (int c2 = 0; c2 < 4; ++c2) {
      if (AF32) {
        const float* p = (const float*)Av + aoff[c2] + kc;
        f32x4 x0 = *(const f32x4*)p;
        f32x4 x1 = *(const f32x4*)(p + 4);
#pragma unroll
        for (int j = 0; j < 4; ++j) {
          ar[c2][j] = (short)f2bf(x0[j]);
          ar[c2][4 + j] = (short)f2bf(x1[j]);
        }
      } else {
        ar[c2] = *(const bf16x8*)((const ushort*)Av + aoff[c2] + kc);
      }
      br[c2] = *(const bf16x8*)(brow[c2] + kc);
    }
    __syncthreads();
#pragma unroll
    for (int c2 = 0; c2 < 4; ++c2) {
      *(bf16x8*)(At + swz(c2 * 32 + srow, skof)) = ar[c2];
      *(bf16x8*)(Bt + swz(c2 * 32 + srow, skof)) = br[c2];
    }
    __syncthreads();
#pragma unroll
    for (int ks = 0; ks < 2; ++ks) {
      bf16x8 af[4], bfr[4];
#pragma unroll
      for (int mt = 0; mt < 4; ++mt)
        af[mt] = *(const bf16x8*)(At + swz(wr * 64 + mt * 16 + lr, ks * 32 + lk));
#pragma unroll
      for (int nt = 0; nt < 4; ++nt)
        bfr[nt] = *(const bf16x8*)(Bt + swz(wc * 64 + nt * 16 + lr, ks * 32 + lk));
#pragma unroll
      for (int mt = 0; mt < 4; ++mt)
#pragma unroll
        for (int nt = 0; nt < 4; ++nt)
          acc[mt][nt] = __builtin_amdgcn_mfma_f32_16x16x32_bf16(af[mt], bfr[nt], acc[mt][nt], 0, 0, 0);
    }
  }

#pragma unroll
  for (int mt = 0; mt < 4; ++mt) {
#pragma unroll
    for (int nt = 0; nt < 4; ++nt) {
      int ncol = bx * 128 + wc * 64 + nt * 16 + lr;
      float bv = bias[ncol];
#pragma unroll
      for (int j = 0; j < 4; ++j) {
        int r = by * 128 + wr * 64 + mt * 16 + (l >> 4) * 4 + j;
        G[(size_t)r * 4096 + ncol] = f2bf(acc[mt][nt][j] + bv);
      }
    }
  }
}

// ---------------- one LSTM timestep --------------------------------------------
// grid 256 = 64 ch-tiles x 4 batch-tiles, block 64 (1 wave).
// wave: 16 batch rows x 16 h-cols x 4 gates, K=1024 via 128 MFMAs.
template <bool OUTF32>
__global__ __launch_bounds__(64) void lstm_step(const ushort* __restrict__ hprev,
                                                ushort* __restrict__ hnext,
                                                float* __restrict__ cbuf,
                                                const ushort* __restrict__ WhT,  // [4096][1024]
                                                const ushort* __restrict__ Gt,   // [64][4096]
                                                void* __restrict__ outp,
                                                long out_rstride,
                                                const int* __restrict__ lens,
                                                int t) {
  int bx = blockIdx.x & 63;       // ch tile
  int by = blockIdx.x >> 6;       // batch tile 0..3
  int l = threadIdx.x;
  int lr = l & 15, lk = (l >> 4) * 8;

  const ushort* arow = hprev + (by * 16 + lr) * 1024 + lk;
  const ushort* brow = WhT + (size_t)(bx * 16 + lr) * 1024 + lk;

  f32x4 zero = {0.f, 0.f, 0.f, 0.f};
  f32x4 acc[4];
  acc[0] = zero; acc[1] = zero; acc[2] = zero; acc[3] = zero;

#pragma unroll 8
  for (int ks = 0; ks < 32; ++ks) {
    bf16x8 a = *(const bf16x8*)(arow + ks * 32);
#pragma unroll
    for (int g = 0; g < 4; ++g) {
      bf16x8 b = *(const bf16x8*)(brow + (size_t)g * (1024 * 1024) + ks * 32);
      acc[g] = __builtin_amdgcn_mfma_f32_16x16x32_bf16(a, b, acc[g], 0, 0, 0);
    }
  }

  int ch = bx * 16 + lr;
#pragma unroll
  for (int j = 0; j < 4; ++j) {
    int rr = by * 16 + (l >> 4) * 4 + j;
    const ushort* grow = Gt + (size_t)rr * 4096 + ch;
    float gi = acc[0][j] + bf2f(grow[0]);
    float gf = acc[1][j] + bf2f(grow[1024]);
    float gn = acc[2][j] + bf2f(grow[2048]);
    float go = acc[3][j] + bf2f(grow[3072]);
    float i_ = 1.f / (1.f + expf(-gi));
    float f_ = 1.f / (1.f + expf(-gf));
    float n_ = tanhf(gn);
    float o_ = 1.f / (1.f + expf(-go));
    int ci = rr * 1024 + ch;
    float cn = f_ * cbuf[ci] + i_ * n_;
    cbuf[ci] = cn;
    float hv = o_ * tanhf(cn);
    hnext[ci] = f2bf(hv);
    if (OUTF32) {
      float ov = (t < lens[rr]) ? hv : 0.f;
      ((float*)outp)[(size_t)rr * out_rstride + ch] = ov;
    } else {
      ((ushort*)outp)[(size_t)rr * out_rstride + ch] = f2bf(hv);
    }
  }
}

__global__ __launch_bounds__(256) void init_hc(ushort* h, float* c) {
  int i = blockIdx.x * 256 + threadIdx.x;
  h[i] = 0;
  c[i] = 0.f;
}

__global__ __launch_bounds__(256) void write_states(const ushort* __restrict__ h,
                                                    const float* __restrict__ c,
                                                    float* __restrict__ oh,
                                                    float* __restrict__ oc) {
  int i = blockIdx.x * 256 + threadIdx.x;
  oh[i] = bf2f(h[i]);
  oc[i] = c[i];
}

extern "C" void kernel_launch(void* const* d_in, const int* in_sizes, int n_in,
                              void* d_out, int out_size, void* d_ws, size_t ws_size,
                              hipStream_t stream) {
  (void)in_sizes; (void)n_in; (void)out_size; (void)ws_size;
  const int* src    = (const int*)d_in[0];
  const int* lens   = (const int*)d_in[1];
  const float* emb  = (const float*)d_in[2];
  const float* Wx0  = (const float*)d_in[3];
  const float* Wh0  = (const float*)d_in[4];
  const float* b0   = (const float*)d_in[5];
  const float* Wx1  = (const float*)d_in[6];
  const float* Wh1  = (const float*)d_in[7];
  const float* b1   = (const float*)d_in[8];
  float* out = (float*)d_out;

  char* ws = (char*)d_ws;
  ushort* Wx0T = (ushort*)(ws + 0);          // bf16 [4096][512]
  ushort* Wh0T = (ushort*)(ws + 4194304);    // bf16 [4096][1024]
  ushort* Wx1T = (ushort*)(ws + 12582912);   // bf16 [4096][1024]
  ushort* Wh1T = (ushort*)(ws + 20971520);   // bf16 [4096][1024]
  ushort* G    = (ushort*)(ws + 29360128);   // bf16 [4096][4096] (one 64-step chunk)
  ushort* X1   = (ushort*)(ws + 62914560);   // bf16 [256][64][1024]
  ushort* hA   = (ushort*)(ws + 96468992);   // bf16 [64][1024]
  ushort* hB   = (ushort*)(ws + 96600064);   // bf16 [64][1024]
  float*  cbuf = (float*) (ws + 96731136);   // f32  [64][1024]

  transpose_cvt<<<dim3(64, 8),  256, 0, stream>>>(Wx0, Wx0T, 512);
  transpose_cvt<<<dim3(64, 16), 256, 0, stream>>>(Wh0, Wh0T, 1024);
  transpose_cvt<<<dim3(64, 16), 256, 0, stream>>>(Wx1, Wx1T, 1024);
  transpose_cvt<<<dim3(64, 16), 256, 0, stream>>>(Wh1, Wh1T, 1024);

  // ---- layer 0 (A = gathered f32 emb rows)
  init_hc<<<256, 256, 0, stream>>>(hA, cbuf);
  for (int c = 0; c < 4; ++c) {
    gemm_xw<true><<<1024, 256, 0, stream>>>(emb, src, c * 64, Wx0T, b0, G, 512);
    for (int tl = 0; tl < 64; ++tl) {
      int t = c * 64 + tl;
      const ushort* hp = (t & 1) ? hB : hA;
      ushort* hn = (t & 1) ? hA : hB;
      lstm_step<false><<<256, 64, 0, stream>>>(hp, hn, cbuf, Wh0T, G + (size_t)tl * 262144,
                                               X1 + (size_t)t * 65536, 1024, nullptr, t);
    }
  }
  write_states<<<256, 256, 0, stream>>>(hA, cbuf, out + 16777216, out + 16908288);

  // ---- layer 1 (A = bf16 X1 rows)
  init_hc<<<256, 256, 0, stream>>>(hA, cbuf);
  for (int c = 0; c < 4; ++c) {
    gemm_xw<false><<<1024, 256, 0, stream>>>(X1 + (size_t)c * 4194304, nullptr, 0, Wx1T, b1, G, 1024);
    for (int tl = 0; tl < 64; ++tl) {
      int t = c * 64 + tl;
      const ushort* hp = (t & 1) ? hB : hA;
      ushort* hn = (t & 1) ? hA : hB;
      lstm_step<true><<<256, 64, 0, stream>>>(hp, hn, cbuf, Wh1T, G + (size_t)tl * 262144,
                                              out + (size_t)t * 1024, 262144, lens, t);
    }
  }
  write_states<<<256, 256, 0, stream>>>(hA, cbuf, out + 16777216 + 65536, out + 16908288 + 65536);
}